// Round 1
// 1010.201 us; speedup vs baseline: 1.0095x; 1.0095x over previous
//
#include <hip/hip_runtime.h>
#include <cstdint>
#include <cstddef>

// ---------------------------------------------------------------------------
// AttentionLayer collapse: logit[i,k] = sum_a G1[a]*u_s[i,a] + G2[a]*u_n[i,k,a] + C
// where u = X@W (bf16 MFMA product, also stored for pass 2),
// G1 = inv_s*gamma*w1, G2 = inv_n*gamma*w2,
// C  = b_out + sum_a beta*(w1+w2) - ms*G1 - mn*G2.  (b_shared cancels in BN.)
// Pass 1 (stats_gemm2): barrier-free K-loop — A direct global->reg (no LDS,
// no reuse exists for A), full Wt resident in LDS, register-resident column
// sum/sumsq across tiles. Pass 2 reads bf16 u only (4x smaller than X).
// ---------------------------------------------------------------------------

typedef __attribute__((ext_vector_type(8))) short short8;   // 8 bf16 (4 VGPRs)
typedef __attribute__((ext_vector_type(4))) float float4v;  // MFMA C/D frag

__device__ __forceinline__ unsigned short f2bf(float f) {
  union { float f; unsigned u; } v; v.f = f;
  unsigned r = v.u + 0x7FFFu + ((v.u >> 16) & 1u);  // RNE
  return (unsigned short)(r >> 16);
}
__device__ __forceinline__ float bfu(unsigned v) {  // low 16 bits -> float
  union { unsigned u; float f; } t; t.u = v << 16; return t.f;
}
__device__ __forceinline__ unsigned pkbf(float x, float y) {
  return (unsigned)f2bf(x) | ((unsigned)f2bf(y) << 16);
}

// W [256,128] fp32 row-major -> Wt [128][256] bf16 (B^T layout for MFMA B-frags)
__global__ __launch_bounds__(256) void transpose_w(const float* __restrict__ W,
                                                   unsigned short* __restrict__ Wt) {
  const int n = blockIdx.x;    // 0..127 (output col a)
  const int k = threadIdx.x;   // 0..255 (feature f)
  Wt[n * 256 + k] = f2bf(W[k * 128 + n]);
}

// ---------------------------------------------------------------------------
// Stats GEMM v2: u = X@W (stored bf16) + per-column sum / sumsq of u.
// X: [R,256] fp32. Tile 128 rows; 4 waves = row quarters (32 rows each,
// acc[2][8] of 16x16x32 bf16 MFMA). Full Wt in LDS (one barrier); A loaded
// straight from global into fragments (each element used by exactly 1 lane).
// K-loop has NO barriers -> loads of chunk k+1 overlap MFMA of chunk k.
// partials[bid*256 + c]: c<128 sum, c>=128 sumsq.
// ---------------------------------------------------------------------------
#define BROW 264  // Bs row stride in bf16: 132-dword stride == 4 mod 32 banks

template <bool GUARD>
__global__ __launch_bounds__(256) void stats_gemm2(
    const float* __restrict__ X, int R, int nTiles,
    const unsigned short* __restrict__ Wt,
    unsigned short* __restrict__ U,          // [R,128] bf16 out
    float* __restrict__ partials) {
  __shared__ __align__(16) unsigned short Bs[128 * BROW];  // 67.6 KB
  __shared__ float cred[1024];  // [0..511] sums [512..1023] sumsq, [wave][col]

  const int tid  = threadIdx.x;
  const int lane = tid & 63;
  const int wv   = tid >> 6;   // 0..3: row quarter within tile
  const int quad = lane >> 4;  // 0..3: k-slice (quad*8) / C-row group
  const int l16  = lane & 15;

  // stage all of Wt ([128 n][256 k] bf16) into LDS once; 16B per thread-iter
#pragma unroll
  for (int it = 0; it < 16; ++it) {
    int e = it * 256 + tid;        // uint4 index, 4096 total
    int r = e >> 5, c = e & 31;    // row, 16B-chunk within row
    *(uint4*)&Bs[r * BROW + c * 8] = *(const uint4*)(Wt + r * 256 + c * 8);
  }
  __syncthreads();  // the only barrier before the epilogue

  float rs[8], rq[8];
#pragma unroll
  for (int cb = 0; cb < 8; ++cb) { rs[cb] = 0.f; rq[cb] = 0.f; }

  for (int t = blockIdx.x; t < nTiles; t += gridDim.x) {
    const int row0 = t * 128 + wv * 32;
    float4v acc[2][8];
#pragma unroll
    for (int rb = 0; rb < 2; ++rb)
#pragma unroll
      for (int cb = 0; cb < 8; ++cb)
        acc[rb][cb] = (float4v){0.f, 0.f, 0.f, 0.f};

#pragma unroll
    for (int kc = 0; kc < 8; ++kc) {
      short8 a[2];
#pragma unroll
      for (int rb = 0; rb < 2; ++rb) {
        const int gr = row0 + rb * 16 + l16;
        float4 v0 = make_float4(0.f, 0.f, 0.f, 0.f);
        float4 v1 = make_float4(0.f, 0.f, 0.f, 0.f);
        if (!GUARD || gr < R) {
          const float* p = X + (size_t)gr * 256 + kc * 32 + quad * 8;
          v0 = *(const float4*)p;
          v1 = *(const float4*)(p + 4);
        }
        union { short8 s; unsigned u[4]; } af;
        af.u[0] = pkbf(v0.x, v0.y);
        af.u[1] = pkbf(v0.z, v0.w);
        af.u[2] = pkbf(v1.x, v1.y);
        af.u[3] = pkbf(v1.z, v1.w);
        a[rb] = af.s;
      }
#pragma unroll
      for (int cb = 0; cb < 8; ++cb) {
        short8 b = *(const short8*)&Bs[(cb * 16 + l16) * BROW + kc * 32 + quad * 8];
#pragma unroll
        for (int rb = 0; rb < 2; ++rb)
          acc[rb][cb] = __builtin_amdgcn_mfma_f32_16x16x32_bf16(
              a[rb], b, acc[rb][cb], 0, 0, 0);
      }
    }

    // Store u (bf16) + accumulate stats in registers.
    // C/D layout: col = cb*16 + l16, row = rb*16 + quad*4 + rg.
#pragma unroll
    for (int rb = 0; rb < 2; ++rb) {
#pragma unroll
      for (int cb = 0; cb < 8; ++cb) {
        const int col = cb * 16 + l16;
#pragma unroll
        for (int rg = 0; rg < 4; ++rg) {
          const int grow = row0 + rb * 16 + quad * 4 + rg;
          const float x = acc[rb][cb][rg];
          if (!GUARD || grow < R) U[(size_t)grow * 128 + col] = f2bf(x);
          rs[cb] += x;                 // guarded rows have x == 0 exactly
          rq[cb] = fmaf(x, x, rq[cb]);
        }
      }
    }
  }

  // epilogue: quad-reduce then cross-wave reduce via LDS (Bs no longer read)
#pragma unroll
  for (int cb = 0; cb < 8; ++cb) {
    float s = rs[cb], q = rq[cb];
    s += __shfl_xor(s, 16); s += __shfl_xor(s, 32);
    q += __shfl_xor(q, 16); q += __shfl_xor(q, 32);
    if (quad == 0) {
      cred[wv * 128 + cb * 16 + l16] = s;
      cred[512 + wv * 128 + cb * 16 + l16] = q;
    }
  }
  __syncthreads();
  float out = 0.f;
  if (tid < 128) {
#pragma unroll
    for (int w = 0; w < 4; ++w) out += cred[w * 128 + tid];
  } else {
#pragma unroll
    for (int w = 0; w < 4; ++w) out += cred[512 + w * 128 + (tid - 128)];
  }
  partials[(size_t)blockIdx.x * 256 + tid] = out;
}

// stats[0..255] = self (sum|sumsq), stats[256..511] = neigh
__global__ __launch_bounds__(256) void reduce_partials(
    const float* __restrict__ ps, int ns, const float* __restrict__ pn, int nn,
    float* __restrict__ stats) {
  __shared__ float buf[256];
  const int c = blockIdx.x;    // 0..255
  const int tid = threadIdx.x;
  float a = 0.f;
  for (int g = tid; g < ns; g += 256) a += ps[(size_t)g * 256 + c];
  buf[tid] = a;
  __syncthreads();
  for (int s = 128; s > 0; s >>= 1) {
    if (tid < s) buf[tid] += buf[tid + s];
    __syncthreads();
  }
  if (tid == 0) stats[c] = buf[0];
  float b = 0.f;
  for (int g = tid; g < nn; g += 256) b += pn[(size_t)g * 256 + c];
  __syncthreads();
  buf[tid] = b;
  __syncthreads();
  for (int s = 128; s > 0; s >>= 1) {
    if (tid < s) buf[tid] += buf[tid + s];
    __syncthreads();
  }
  if (tid == 0) stats[256 + c] = buf[0];
}

// one block: fold BN + Dense(2A->1) into G1[128], G2[128], C
__global__ __launch_bounds__(128) void setup_kernel(
    const float* __restrict__ stats,
    const float* __restrict__ gamma, const float* __restrict__ beta,
    const float* __restrict__ Wout, const float* __restrict__ bout,
    float* __restrict__ G1, float* __restrict__ G2, float* __restrict__ Cout) {
  __shared__ float carr[128];
  const int tid = threadIdx.x;
  const float invNs = 1.f / 20000.f, invNn = 1.f / 640000.f;
  float ms = stats[tid] * invNs;                       // mean of dot (self)
  float vs = stats[128 + tid] * invNs - ms * ms;       // var (b cancels)
  float is = rsqrtf(vs + 1e-3f);
  float mn = stats[256 + tid] * invNn;
  float vn = stats[384 + tid] * invNn - mn * mn;
  float in_ = rsqrtf(vn + 1e-3f);
  float w1 = Wout[tid], w2 = Wout[128 + tid];
  float g1 = is * gamma[tid] * w1;
  float g2 = in_ * gamma[tid] * w2;
  G1[tid] = g1;
  G2[tid] = g2;
  carr[tid] = beta[tid] * (w1 + w2) - ms * g1 - mn * g2;
  __syncthreads();
  if (tid == 0) {
    float c = bout[0];
    for (int a = 0; a < 128; ++a) c += carr[a];
    Cout[0] = c;
  }
}

// one wave per row i: dots against bf16 u + in-wave softmax. No LDS.
__global__ __launch_bounds__(256) void attn_final(
    const unsigned short* __restrict__ Us,   // [20000,128] bf16
    const unsigned short* __restrict__ Un,   // [640000,128] bf16
    const float* __restrict__ G1, const float* __restrict__ G2,
    const float* __restrict__ Cptr, float* __restrict__ out) {
  const int lane = threadIdx.x & 63;
  const int wv = threadIdx.x >> 6;
  const int i = blockIdx.x * 4 + wv;  // 5000*4 = 20000 exact
  const int l16 = lane & 15;
  const int l32 = lane & 31;
  const int quarter = lane >> 4;      // 0..3
  const float C = Cptr[0];

  // self: lane handles elems 2*lane, 2*lane+1
  unsigned su = *(const unsigned*)(Us + (size_t)i * 128 + lane * 2);
  float2 g1p = *(const float2*)(G1 + lane * 2);
  float sd = fmaf(g1p.x, bfu(su), g1p.y * bfu(su >> 16));
#pragma unroll
  for (int m = 32; m >= 1; m >>= 1) sd += __shfl_xor(sd, m);

  // neighbors: 4 per iteration; quarter q handles neighbor 4j+q,
  // lane covers elems l16*8..l16*8+7 (uint4 = 8 bf16 = 16B, wave reads 1KiB).
  const float4 ga = *(const float4*)(G2 + l16 * 8);
  const float4 gb = *(const float4*)(G2 + l16 * 8 + 4);
  const unsigned short* un = Un + (size_t)i * 4096;
  float ml = 0.f;
#pragma unroll
  for (int j = 0; j < 8; ++j) {
    const int nb = j * 4 + quarter;
    uint4 q = *(const uint4*)(un + nb * 128 + l16 * 8);
    float p;
    p = fmaf(ga.x, bfu(q.x), ga.y * bfu(q.x >> 16));
    p = fmaf(ga.z, bfu(q.y), p); p = fmaf(ga.w, bfu(q.y >> 16), p);
    p = fmaf(gb.x, bfu(q.z), p); p = fmaf(gb.y, bfu(q.z >> 16), p);
    p = fmaf(gb.z, bfu(q.w), p); p = fmaf(gb.w, bfu(q.w >> 16), p);
#pragma unroll
    for (int m = 1; m <= 8; m <<= 1) p += __shfl_xor(p, m);
    // p = dot(4j+quarter) on all 16 lanes of this quarter
    float s16 = __shfl_xor(p, 16);     // dot(4j + quarter^1)
    float s32 = __shfl_xor(p, 32);     // dot(4j + quarter^2)
    float s48 = __shfl_xor(s16, 32);   // dot(4j + quarter^3)
    if ((l32 >> 2) == j) {
      int x = (l32 & 3) ^ quarter;
      ml = (x == 0) ? p : (x == 1) ? s16 : (x == 2) ? s32 : s48;
    }
  }
  float logit = fmaxf(ml + sd + C, 0.f);
  float mx = logit;
#pragma unroll
  for (int m = 16; m >= 1; m >>= 1) mx = fmaxf(mx, __shfl_xor(mx, m));
  float e = __expf(logit - mx);
  float ssum = e;
#pragma unroll
  for (int m = 16; m >= 1; m >>= 1) ssum += __shfl_xor(ssum, m);
  if (lane < 32) out[(size_t)i * 32 + lane] = e / ssum;
}

extern "C" void kernel_launch(void* const* d_in, const int* in_sizes, int n_in,
                              void* d_out, int out_size, void* d_ws, size_t ws_size,
                              hipStream_t stream) {
  const float* self  = (const float*)d_in[0];  // [20000,256]
  const float* neigh = (const float*)d_in[1];  // [20000,32,256]
  const float* W     = (const float*)d_in[2];  // [256,128]
  // d_in[3] = b_shared: cancels in BN, unused
  const float* gamma = (const float*)d_in[4];
  const float* beta  = (const float*)d_in[5];
  const float* Wout  = (const float*)d_in[6];  // [256,1]
  const float* bout  = (const float*)d_in[7];
  float* out = (float*)d_out;

  // workspace layout (~170.3 MB)
  char* ws = (char*)d_ws;
  unsigned short* Wt = (unsigned short*)ws;              // 64 KiB
  unsigned short* Us = (unsigned short*)(ws + (1 << 16));          // 5.12 MB
  unsigned short* Un = Us + (size_t)20000 * 128;                   // 163.84 MB
  float* part_s = (float*)(Un + (size_t)640000 * 128);   // 157*256
  float* part_n = part_s + 157 * 256;                    // 1024*256
  float* stats  = part_n + 1024 * 256;                   // 512
  float* G1     = stats + 512;                           // 128
  float* G2     = G1 + 128;                              // 128
  float* Cc     = G2 + 128;                              // 1

  hipLaunchKernelGGL(transpose_w, dim3(128), dim3(256), 0, stream, W, Wt);
  hipLaunchKernelGGL((stats_gemm2<true>), dim3(157), dim3(256), 0, stream,
                     self, 20000, 157, Wt, Us, part_s);
  hipLaunchKernelGGL((stats_gemm2<false>), dim3(1000), dim3(256), 0, stream,
                     neigh, 640000, 5000, Wt, Un, part_n);
  hipLaunchKernelGGL(reduce_partials, dim3(256), dim3(256), 0, stream,
                     part_s, 157, part_n, 1000, stats);
  hipLaunchKernelGGL(setup_kernel, dim3(1), dim3(128), 0, stream,
                     stats, gamma, beta, Wout, bout, G1, G2, Cc);
  hipLaunchKernelGGL(attn_final, dim3(5000), dim3(256), 0, stream,
                     Us, Un, G1, G2, Cc, out);
}

// Round 2
// 983.867 us; speedup vs baseline: 1.0365x; 1.0268x over previous
//
#include <hip/hip_runtime.h>
#include <cstdint>
#include <cstddef>

// ---------------------------------------------------------------------------
// AttentionLayer collapse: logit[i,k] = sum_a G1[a]*u_s[i,a] + G2[a]*u_n[i,k,a] + C
// where u = X@W (bf16 MFMA product, also stored for pass 2),
// G1 = inv_s*gamma*w1, G2 = inv_n*gamma*w2,
// C  = b_out + sum_a beta*(w1+w2) - ms*G1 - mn*G2.  (b_shared cancels in BN.)
//
// 3 dispatches total:
//  K1 fused_stats: self+neigh in one grid; W transposed fp32->bf16 into LDS
//     per block (no Wt buffer); barrier-free K-loop, A direct global->reg;
//     register-resident column sum/sumsq.
//  K2 reduce_partials: column-wise tree over per-block partials -> stats[512].
//  K3 attn_final: BN+Dense fold (setup) in prologue from stats, then per-row
//     dots against bf16 u + in-wave softmax.
// ---------------------------------------------------------------------------

typedef __attribute__((ext_vector_type(8))) short short8;   // 8 bf16 (4 VGPRs)
typedef __attribute__((ext_vector_type(4))) float float4v;  // MFMA C/D frag

__device__ __forceinline__ unsigned short f2bf(float f) {
  union { float f; unsigned u; } v; v.f = f;
  unsigned r = v.u + 0x7FFFu + ((v.u >> 16) & 1u);  // RNE
  return (unsigned short)(r >> 16);
}
__device__ __forceinline__ float bfu(unsigned v) {  // low 16 bits -> float
  union { unsigned u; float f; } t; t.u = v << 16; return t.f;
}
__device__ __forceinline__ unsigned pkbf(float x, float y) {
  return (unsigned)f2bf(x) | ((unsigned)f2bf(y) << 16);
}

// ---------------------------------------------------------------------------
// K1: u = X@W (stored bf16) + per-column sum / sumsq of u.
// blocks [0,1000): neigh, 5 tiles each (exactly even).
// blocks [1000,1157): self, 1 guarded tile each.
// 4 waves = row quarters (32 rows each, acc[2][8] of 16x16x32 bf16 MFMA).
// Full W^T in LDS (one barrier), built straight from fp32 W.
// K-loop has NO barriers -> loads of chunk k+1 overlap MFMA of chunk k.
// partials[group*256 + c]: c<128 sum, c>=128 sumsq.
// ---------------------------------------------------------------------------
#define BROW 264  // Bs row stride in bf16: 132-dword stride == 4 mod 32 banks
#define NBLK_N 1000
#define NBLK_S 157

__global__ __launch_bounds__(256) void fused_stats(
    const float* __restrict__ Xn, const float* __restrict__ Xs,
    const float* __restrict__ W,             // [256,128] fp32
    unsigned short* __restrict__ Un, unsigned short* __restrict__ Us,
    float* __restrict__ part_n, float* __restrict__ part_s) {
  __shared__ __align__(16) unsigned short Bs[128 * BROW];  // 67.6 KB
  __shared__ float cred[1024];  // [0..511] sums [512..1023] sumsq, [wave][col]

  const int tid  = threadIdx.x;
  const int lane = tid & 63;
  const int wv   = tid >> 6;   // 0..3: row quarter within tile
  const int quad = lane >> 4;  // 0..3: k-slice (quad*8) / C-row group
  const int l16  = lane & 15;

  // role select (block-uniform)
  const float* X; unsigned short* U; float* P;
  int R, t0, tStride, nT; bool guard;
  if (blockIdx.x < NBLK_N) {
    X = Xn; U = Un; P = part_n + (size_t)blockIdx.x * 256;
    R = 640000; t0 = blockIdx.x; tStride = NBLK_N; nT = 5000; guard = false;
  } else {
    int b = blockIdx.x - NBLK_N;
    X = Xs; U = Us; P = part_s + (size_t)b * 256;
    R = 20000; t0 = b; tStride = NBLK_S; nT = NBLK_S; guard = true;
  }

  // build Bs[n][k] = bf16(W[k][n]) straight from fp32 W (fused transpose).
  // thread covers (k = e>>5, 4 n's at (e&31)*4); W row read as float4.
#pragma unroll
  for (int it = 0; it < 32; ++it) {
    int e = it * 256 + tid;
    int k = e >> 5, ng = e & 31;
    float4 w = *(const float4*)(W + k * 128 + ng * 4);
    Bs[(ng * 4 + 0) * BROW + k] = f2bf(w.x);
    Bs[(ng * 4 + 1) * BROW + k] = f2bf(w.y);
    Bs[(ng * 4 + 2) * BROW + k] = f2bf(w.z);
    Bs[(ng * 4 + 3) * BROW + k] = f2bf(w.w);
  }
  __syncthreads();  // the only barrier before the epilogue

  float rs[8], rq[8];
#pragma unroll
  for (int cb = 0; cb < 8; ++cb) { rs[cb] = 0.f; rq[cb] = 0.f; }

  for (int t = t0; t < nT; t += tStride) {
    const int row0 = t * 128 + wv * 32;
    bool ok[2];
    ok[0] = !guard || (row0 + 0 * 16 + l16) < R;
    ok[1] = !guard || (row0 + 1 * 16 + l16) < R;

    float4v acc[2][8];
#pragma unroll
    for (int rb = 0; rb < 2; ++rb)
#pragma unroll
      for (int cb = 0; cb < 8; ++cb)
        acc[rb][cb] = (float4v){0.f, 0.f, 0.f, 0.f};

#pragma unroll
    for (int kc = 0; kc < 8; ++kc) {
      short8 a[2];
#pragma unroll
      for (int rb = 0; rb < 2; ++rb) {
        const int gr = row0 + rb * 16 + l16;
        float4 v0 = make_float4(0.f, 0.f, 0.f, 0.f);
        float4 v1 = make_float4(0.f, 0.f, 0.f, 0.f);
        if (ok[rb]) {
          const float* p = X + (size_t)gr * 256 + kc * 32 + quad * 8;
          v0 = *(const float4*)p;
          v1 = *(const float4*)(p + 4);
        }
        union { short8 s; unsigned u[4]; } af;
        af.u[0] = pkbf(v0.x, v0.y);
        af.u[1] = pkbf(v0.z, v0.w);
        af.u[2] = pkbf(v1.x, v1.y);
        af.u[3] = pkbf(v1.z, v1.w);
        a[rb] = af.s;
      }
#pragma unroll
      for (int cb = 0; cb < 8; ++cb) {
        short8 b = *(const short8*)&Bs[(cb * 16 + l16) * BROW + kc * 32 + quad * 8];
#pragma unroll
        for (int rb = 0; rb < 2; ++rb)
          acc[rb][cb] = __builtin_amdgcn_mfma_f32_16x16x32_bf16(
              a[rb], b, acc[rb][cb], 0, 0, 0);
      }
    }

    // Store u (bf16) + accumulate stats in registers.
    // C/D layout: col = cb*16 + l16, row = rb*16 + quad*4 + rg.
#pragma unroll
    for (int rb = 0; rb < 2; ++rb) {
#pragma unroll
      for (int cb = 0; cb < 8; ++cb) {
        const int col = cb * 16 + l16;
#pragma unroll
        for (int rg = 0; rg < 4; ++rg) {
          const int grow = row0 + rb * 16 + quad * 4 + rg;
          const float x = acc[rb][cb][rg];
          if (!guard || grow < R) U[(size_t)grow * 128 + col] = f2bf(x);
          rs[cb] += x;                 // guarded rows have x == 0 exactly
          rq[cb] = fmaf(x, x, rq[cb]);
        }
      }
    }
  }

  // epilogue: quad-reduce then cross-wave reduce via LDS (Bs no longer read)
#pragma unroll
  for (int cb = 0; cb < 8; ++cb) {
    float s = rs[cb], q = rq[cb];
    s += __shfl_xor(s, 16); s += __shfl_xor(s, 32);
    q += __shfl_xor(q, 16); q += __shfl_xor(q, 32);
    if (quad == 0) {
      cred[wv * 128 + cb * 16 + l16] = s;
      cred[512 + wv * 128 + cb * 16 + l16] = q;
    }
  }
  __syncthreads();
  float out = 0.f;
  if (tid < 128) {
#pragma unroll
    for (int w = 0; w < 4; ++w) out += cred[w * 128 + tid];
  } else {
#pragma unroll
    for (int w = 0; w < 4; ++w) out += cred[512 + w * 128 + (tid - 128)];
  }
  P[tid] = out;
}

// K2: stats[0..255] = self (sum|sumsq), stats[256..511] = neigh
__global__ __launch_bounds__(256) void reduce_partials(
    const float* __restrict__ ps, int ns, const float* __restrict__ pn, int nn,
    float* __restrict__ stats) {
  __shared__ float buf[256];
  const int c = blockIdx.x;    // 0..255
  const int tid = threadIdx.x;
  float a = 0.f;
  for (int g = tid; g < ns; g += 256) a += ps[(size_t)g * 256 + c];
  buf[tid] = a;
  __syncthreads();
  for (int s = 128; s > 0; s >>= 1) {
    if (tid < s) buf[tid] += buf[tid + s];
    __syncthreads();
  }
  if (tid == 0) stats[c] = buf[0];
  float b = 0.f;
  for (int g = tid; g < nn; g += 256) b += pn[(size_t)g * 256 + c];
  __syncthreads();
  buf[tid] = b;
  __syncthreads();
  for (int s = 128; s > 0; s >>= 1) {
    if (tid < s) buf[tid] += buf[tid + s];
    __syncthreads();
  }
  if (tid == 0) stats[256 + c] = buf[0];
}

// K3: setup (BN + Dense(2A->1) fold) in prologue, then one wave per row i:
// dots against bf16 u + in-wave softmax.
__global__ __launch_bounds__(256) void attn_final(
    const unsigned short* __restrict__ Us,   // [20000,128] bf16
    const unsigned short* __restrict__ Un,   // [640000,128] bf16
    const float* __restrict__ stats,
    const float* __restrict__ gamma, const float* __restrict__ beta,
    const float* __restrict__ Wout, const float* __restrict__ bout,
    float* __restrict__ out) {
  __shared__ __align__(16) float sG1[128];
  __shared__ __align__(16) float sG2[128];
  __shared__ float sCarr[128];
  __shared__ float sC;

  const int tid = threadIdx.x;
  // ---- fused setup: fold BN + Dense into G1[128], G2[128], C ----
  if (tid < 128) {
    const float invNs = 1.f / 20000.f, invNn = 1.f / 640000.f;
    float ms = stats[tid] * invNs;                       // mean of dot (self)
    float vs = stats[128 + tid] * invNs - ms * ms;       // var (b cancels)
    float is = rsqrtf(vs + 1e-3f);
    float mn = stats[256 + tid] * invNn;
    float vn = stats[384 + tid] * invNn - mn * mn;
    float in_ = rsqrtf(vn + 1e-3f);
    float w1 = Wout[tid], w2 = Wout[128 + tid];
    float g1 = is * gamma[tid] * w1;
    float g2 = in_ * gamma[tid] * w2;
    sG1[tid] = g1;
    sG2[tid] = g2;
    sCarr[tid] = beta[tid] * (w1 + w2) - ms * g1 - mn * g2;
  }
  __syncthreads();
  if (tid < 64) {
    float c = sCarr[tid] + sCarr[tid + 64];
#pragma unroll
    for (int m = 32; m >= 1; m >>= 1) c += __shfl_xor(c, m);
    if (tid == 0) sC = c + bout[0];
  }
  __syncthreads();

  const int lane = tid & 63;
  const int wv = tid >> 6;
  const int i = blockIdx.x * 4 + wv;  // 5000*4 = 20000 exact
  const int l16 = lane & 15;
  const int l32 = lane & 31;
  const int quarter = lane >> 4;      // 0..3
  const float C = sC;

  // self: lane handles elems 2*lane, 2*lane+1
  unsigned su = *(const unsigned*)(Us + (size_t)i * 128 + lane * 2);
  float2 g1p = *(const float2*)(sG1 + lane * 2);
  float sd = fmaf(g1p.x, bfu(su), g1p.y * bfu(su >> 16));
#pragma unroll
  for (int m = 32; m >= 1; m >>= 1) sd += __shfl_xor(sd, m);

  // neighbors: 4 per iteration; quarter q handles neighbor 4j+q,
  // lane covers elems l16*8..l16*8+7 (uint4 = 8 bf16 = 16B, wave reads 1KiB).
  const float4 ga = *(const float4*)(sG2 + l16 * 8);
  const float4 gb = *(const float4*)(sG2 + l16 * 8 + 4);
  const unsigned short* un = Un + (size_t)i * 4096;
  float ml = 0.f;
#pragma unroll
  for (int j = 0; j < 8; ++j) {
    const int nb = j * 4 + quarter;
    uint4 q = *(const uint4*)(un + nb * 128 + l16 * 8);
    float p;
    p = fmaf(ga.x, bfu(q.x), ga.y * bfu(q.x >> 16));
    p = fmaf(ga.z, bfu(q.y), p); p = fmaf(ga.w, bfu(q.y >> 16), p);
    p = fmaf(gb.x, bfu(q.z), p); p = fmaf(gb.y, bfu(q.z >> 16), p);
    p = fmaf(gb.z, bfu(q.w), p); p = fmaf(gb.w, bfu(q.w >> 16), p);
#pragma unroll
    for (int m = 1; m <= 8; m <<= 1) p += __shfl_xor(p, m);
    // p = dot(4j+quarter) on all 16 lanes of this quarter
    float s16 = __shfl_xor(p, 16);     // dot(4j + quarter^1)
    float s32 = __shfl_xor(p, 32);     // dot(4j + quarter^2)
    float s48 = __shfl_xor(s16, 32);   // dot(4j + quarter^3)
    if ((l32 >> 2) == j) {
      int x = (l32 & 3) ^ quarter;
      ml = (x == 0) ? p : (x == 1) ? s16 : (x == 2) ? s32 : s48;
    }
  }
  float logit = fmaxf(ml + sd + C, 0.f);
  float mx = logit;
#pragma unroll
  for (int m = 16; m >= 1; m >>= 1) mx = fmaxf(mx, __shfl_xor(mx, m));
  float e = __expf(logit - mx);
  float ssum = e;
#pragma unroll
  for (int m = 16; m >= 1; m >>= 1) ssum += __shfl_xor(ssum, m);
  if (lane < 32) out[(size_t)i * 32 + lane] = e / ssum;
}

extern "C" void kernel_launch(void* const* d_in, const int* in_sizes, int n_in,
                              void* d_out, int out_size, void* d_ws, size_t ws_size,
                              hipStream_t stream) {
  const float* self  = (const float*)d_in[0];  // [20000,256]
  const float* neigh = (const float*)d_in[1];  // [20000,32,256]
  const float* W     = (const float*)d_in[2];  // [256,128]
  // d_in[3] = b_shared: cancels in BN, unused
  const float* gamma = (const float*)d_in[4];
  const float* beta  = (const float*)d_in[5];
  const float* Wout  = (const float*)d_in[6];  // [256,1]
  const float* bout  = (const float*)d_in[7];
  float* out = (float*)d_out;

  // workspace layout (~170.2 MB)
  char* ws = (char*)d_ws;
  unsigned short* Us = (unsigned short*)ws;              // 5.12 MB
  unsigned short* Un = Us + (size_t)20000 * 128;         // 163.84 MB
  float* part_s = (float*)(Un + (size_t)640000 * 128);   // 157*256
  float* part_n = part_s + NBLK_S * 256;                 // 1000*256
  float* stats  = part_n + NBLK_N * 256;                 // 512

  hipLaunchKernelGGL(fused_stats, dim3(NBLK_N + NBLK_S), dim3(256), 0, stream,
                     neigh, self, W, Un, Us, part_n, part_s);
  hipLaunchKernelGGL(reduce_partials, dim3(256), dim3(256), 0, stream,
                     part_s, NBLK_S, part_n, NBLK_N, stats);
  hipLaunchKernelGGL(attn_final, dim3(5000), dim3(256), 0, stream,
                     Us, Un, stats, gamma, beta, Wout, bout, out);
}